// Round 3
// baseline (234.584 us; speedup 1.0000x reference)
//
#include <hip/hip_runtime.h>
#include <math.h>

#define G    64
#define NPG  2048
#define EPG  (NPG * 8)          // 16384 edges per graph
#define KSEL 410
#define NH   3
#define NC   20
#define HC   60
#define FCAP 24
#define RP   12                 // x1g padded row: x1[0..9], dinv@10, hs@11 (48 B)
#define QN   512                // nodes per quarter (D1)
#define PS   128                // p-slice per block (D2)

#define QSCALE 33554432.0f              // 2^25 (int-quantized scorer scatter)
#define QINV   2.9802322387695312e-8f   // 2^-25

// ---------------- D1 arena (quarter-CSR GCN) — verbatim round-1 layout ----------------
#define A1_H1P   0              // 98304  h1p 2048x12f
#define A1_HIST  98304          // 8192   full-graph degree hist (int)
#define A1_RSQ   106496         // 2064   rsQ[513] int
#define A1_CURQ  108560         // 2048   curQ[512] int
#define A1_CSRQ  110608         // 32768  csrQ u16[16384]
#define A1_WSUM  143376         // 64
#define A1_SZ    143440

// ---------------- D2 arena ----------------
// hf region [0,98400) is written only in P7; early phases alias inside it.
#define B_HF     0              // 98400  hf 410x60f           [P7..P8]
#define B_PRF    0              // 8192   prF float[2048]      [P0..P2]
#define B_SUMI   8192           // 8192   sumI int[2048]       [P0..P2]
#define B_DIL    16384          // 8192   diL float[2048]      [P0..P2]
#define B_HIST   24576          // 8192   radix hist int[2048] [P0..P4]
#define B_XPL    98400          // 16400  xp 410x10f           [P5..P7]
#define B_ALS    114800         // 4920   als                  [P7..P8]
#define B_ALD    119720        // 4920   ald                  [P7..P8]
#define B_SKL    124640         // 8192   keys u32             [P2..P5]
#define B_NEWL   132832         // 4096   newL u16             [P0..P6]
#define B_PERML  136928         // 824    permL u16            [P4..P5]
#define B_FADJ   137752         // 6144   fadjO 128x24 u16     [P5..P8]
#define B_FCNT   143896         // 512    fcntO int[128]       [P5..P8]
#define B_GOUT   144408         // 240    [tail]
#define B_HID    144648         // 120    [tail]
#define B_WSUM   144768         // 64
#define B_FLAGS  144832         // 16
#define B_SZ     144848

__device__ inline float leaky(float x) { return x >= 0.f ? x : 0.2f * x; }

__device__ inline int wave_incl_scan(int v) {
    int lane = threadIdx.x & 63;
#pragma unroll
    for (int d = 1; d < 64; d <<= 1) {
        int t = __shfl_up(v, d, 64);
        if (lane >= d) v += t;
    }
    return v;
}

// ================= D1: GCN(5->10) + scorer pre-dot (round-1 k1, verbatim) =================
__global__ __launch_bounds__(1024) void k1_gcn(
    const float* __restrict__ x, const int* __restrict__ src, const int* __restrict__ dst,
    const float* __restrict__ W1, const float* __restrict__ b1, const float* __restrict__ Ws,
    float* __restrict__ x1g)
{
    __shared__ __align__(16) char arena[A1_SZ];
    float*          h1p   = (float*)(arena + A1_H1P);
    int*            hist  = (int*)(arena + A1_HIST);
    int*            rsQ   = (int*)(arena + A1_RSQ);
    int*            curQ  = (int*)(arena + A1_CURQ);
    unsigned short* csrQ  = (unsigned short*)(arena + A1_CSRQ);
    int*            wsumL = (int*)(arena + A1_WSUM);

    int bx = blockIdx.x, tid = threadIdx.x, wid = tid >> 6;
    int g = bx & 63, q = bx >> 6;     // 4 blocks of a graph share an XCD (64%8==0)
    int nbase = g * NPG, ebase = g * EPG, qbase = q << 9;

    for (int i = tid; i < NPG; i += 1024) hist[i] = 0;
    for (int i = tid; i < NPG; i += 1024) {
        float xi[5];
#pragma unroll
        for (int k = 0; k < 5; k++) xi[k] = x[(size_t)(nbase + i) * 5 + k];
        float v[10];
#pragma unroll
        for (int j = 0; j < 10; j++) {
            float s = 0.f;
#pragma unroll
            for (int k = 0; k < 5; k++) s += xi[k] * W1[k * 10 + j];
            v[j] = s;
        }
        float4* row = (float4*)(h1p + i * RP);
        row[0] = make_float4(v[0], v[1], v[2], v[3]);
        row[1] = make_float4(v[4], v[5], v[6], v[7]);
        row[2] = make_float4(v[8], v[9], 0.f, 0.f);
    }
    __syncthreads();
    for (int e = tid; e < EPG; e += 1024)
        atomicAdd(&hist[dst[ebase + e] - nbase], 1);
    __syncthreads();
    for (int i = tid; i < NPG; i += 1024)
        h1p[i * RP + 10] = rsqrtf((float)hist[i] + 1.0f);
    {
        int dvv = 0;
        if (tid < QN) { dvv = hist[qbase + tid]; curQ[tid] = 0; }
        int incl = wave_incl_scan(dvv);
        if (tid < QN && (tid & 63) == 63) wsumL[wid] = incl;
        __syncthreads();
        if (tid == 0) {
            int a = 0;
#pragma unroll
            for (int w = 0; w < 8; w++) { int t = wsumL[w]; wsumL[w] = a; a += t; }
            rsQ[QN] = a;
        }
        __syncthreads();
        if (tid < QN) rsQ[tid] = wsumL[wid] + incl - dvv;
        __syncthreads();
    }
    for (int e = tid; e < EPG; e += 1024) {
        int ee = ebase + e;
        int dl = dst[ee] - nbase;
        if ((dl >> 9) == q) {
            int j = dl - qbase;
            int pos = rsQ[j] + atomicAdd(&curQ[j], 1);
            csrQ[pos] = (unsigned short)(src[ee] - nbase);
        }
    }
    __syncthreads();
    {
        int p = tid >> 1, half = tid & 1, i = qbase + p;
        float a0 = 0.f, a1 = 0.f, a2 = 0.f, a3 = 0.f, a4 = 0.f;
        float a5 = 0.f, a6 = 0.f, a7 = 0.f, a8 = 0.f, a9 = 0.f;
        int p0 = rsQ[p], p1 = rsQ[p + 1];
        for (int e = p0 + half; e < p1; e += 2) {
            int s = csrQ[e];
            const float4* rw = (const float4*)(h1p + s * RP);
            float4 r0 = rw[0], r1 = rw[1], r2 = rw[2];
            float dv = r2.z;
            a0 += r0.x * dv; a1 += r0.y * dv; a2 += r0.z * dv; a3 += r0.w * dv;
            a4 += r1.x * dv; a5 += r1.y * dv; a6 += r1.z * dv; a7 += r1.w * dv;
            a8 += r2.x * dv; a9 += r2.y * dv;
        }
        a0 += __shfl_xor(a0, 1, 64); a1 += __shfl_xor(a1, 1, 64);
        a2 += __shfl_xor(a2, 1, 64); a3 += __shfl_xor(a3, 1, 64);
        a4 += __shfl_xor(a4, 1, 64); a5 += __shfl_xor(a5, 1, 64);
        a6 += __shfl_xor(a6, 1, 64); a7 += __shfl_xor(a7, 1, 64);
        a8 += __shfl_xor(a8, 1, 64); a9 += __shfl_xor(a9, 1, 64);
        if (half == 0) {
            const float4* rowi = (const float4*)(h1p + i * RP);
            float4 s0 = rowi[0], s1 = rowi[1], s2v = rowi[2];
            float di = s2v.z, d2 = di * di;
            float v[10];
            v[0] = a0 * di + s0.x * d2 + b1[0];
            v[1] = a1 * di + s0.y * d2 + b1[1];
            v[2] = a2 * di + s0.z * d2 + b1[2];
            v[3] = a3 * di + s0.w * d2 + b1[3];
            v[4] = a4 * di + s1.x * d2 + b1[4];
            v[5] = a5 * di + s1.y * d2 + b1[5];
            v[6] = a6 * di + s1.z * d2 + b1[6];
            v[7] = a7 * di + s1.w * d2 + b1[7];
            v[8] = a8 * di + s2v.x * d2 + b1[8];
            v[9] = a9 * di + s2v.y * d2 + b1[9];
            float hs = 0.f;
#pragma unroll
            for (int j = 0; j < 10; j++) hs += v[j] * Ws[j];
            float4* xr = (float4*)(x1g + (size_t)(nbase + i) * RP);
            xr[0] = make_float4(v[0], v[1], v[2], v[3]);
            xr[1] = make_float4(v[4], v[5], v[6], v[7]);
            xr[2] = make_float4(v[8], v[9], di, hs);
        }
    }
}

// ================= D2: scorer(int-scatter) + select + GAT + agg + tail, 4 blocks/graph =================
__global__ __launch_bounds__(1024) void k2_wide(
    const int* __restrict__ src, const int* __restrict__ dst,
    const float* __restrict__ bs, const float* __restrict__ Wg,
    const float* __restrict__ a_srcw, const float* __restrict__ a_dstw,
    const float* __restrict__ bg,
    const float* __restrict__ Wf1, const float* __restrict__ bf1,
    const float* __restrict__ Wf2, const float* __restrict__ bf2,
    const float* __restrict__ x1g, float* __restrict__ gpart, int* __restrict__ tick,
    float* __restrict__ out)
{
    __shared__ __align__(16) char arena[B_SZ];
    float*          hfL   = (float*)(arena + B_HF);
    float*          prF   = (float*)(arena + B_PRF);
    int*            sumI  = (int*)(arena + B_SUMI);
    float*          diL   = (float*)(arena + B_DIL);
    int*            hist  = (int*)(arena + B_HIST);
    float*          xpL   = (float*)(arena + B_XPL);
    float*          alsL  = (float*)(arena + B_ALS);
    float*          aldL  = (float*)(arena + B_ALD);
    unsigned*       skL   = (unsigned*)(arena + B_SKL);
    unsigned short* newLs = (unsigned short*)(arena + B_NEWL);
    unsigned short* permL = (unsigned short*)(arena + B_PERML);
    unsigned short* fadjO = (unsigned short*)(arena + B_FADJ);
    int*            fcntO = (int*)(arena + B_FCNT);
    float*          goutL = (float*)(arena + B_GOUT);
    float*          hidL  = (float*)(arena + B_HID);
    int*            wsumL = (int*)(arena + B_WSUM);
    int*            flags = (int*)(arena + B_FLAGS);
#define bselS  flags[0]
#define bneedS flags[1]
#define lastS  flags[2]
#define totS   flags[3]

    int bx = blockIdx.x, tid = threadIdx.x, wid = tid >> 6;
    int g = bx & 63, q = bx >> 6;
    int nbase = g * NPG, ebase = g * EPG, ps = q * PS;

    // ---- P0: stage (dinv, pr=dinv*hs); zero sums/hist; init newL
    for (int i = tid; i < NPG; i += 1024) {
        float2 dh = *(const float2*)(x1g + (size_t)(nbase + i) * RP + 10);
        diL[i] = dh.x;
        prF[i] = dh.x * dh.y;
        sumI[i] = 0;
        hist[i] = 0;
        newLs[i] = 0xFFFFu;
    }
    __syncthreads();
    // ---- P1: scorer scatter, INTEGER-quantized => associative => identical across blocks
    for (int e = tid; e < EPG; e += 1024) {
        int ee = ebase + e;
        int sl = src[ee] - nbase;
        int dl = dst[ee] - nbase;
        atomicAdd(&sumI[dl], __float2int_rn(prF[sl] * QSCALE));
    }
    __syncthreads();
    // ---- P2: keys (deterministic)
    float bsv = bs[0];
    for (int i = tid; i < NPG; i += 1024) {
        float S = (float)sumI[i] * QINV;
        float sc = diL[i] * (S + prF[i]) + bsv;
        unsigned u = __float_as_uint(sc);
        skL[i] = (u & 0x80000000u) ? ~u : (u | 0x80000000u);
    }
    int need = KSEL;
    unsigned prefix = 0;
    __syncthreads();
    // ---- P3: 3-level radix select (11/11/10 bits)
    for (int lv = 0; lv < 3; lv++) {
        for (int i = tid; i < NPG; i += 1024) {
            unsigned k = skL[i];
            bool match; unsigned bb;
            if (lv == 0)      { match = true;                  bb = k >> 21; }
            else if (lv == 1) { match = ((k >> 21) == prefix); bb = (k >> 10) & 0x7FFu; }
            else              { match = ((k >> 10) == prefix); bb = k & 0x3FFu; }
            if (match) atomicAdd(&hist[bb], 1);
        }
        __syncthreads();
        int b2 = tid * 2;
        int v0 = hist[b2], v1 = hist[b2 + 1];
        hist[b2] = 0; hist[b2 + 1] = 0;
        int s = v0 + v1;
        int incl = wave_incl_scan(s);
        if ((tid & 63) == 63) wsumL[wid] = incl;
        __syncthreads();
        if (tid == 0) {
            int a = 0;
#pragma unroll
            for (int w = 0; w < 16; w++) { int t = wsumL[w]; wsumL[w] = a; a += t; }
            totS = a;
        }
        __syncthreads();
        int base = wsumL[wid] + incl - s;
        int tot = totS;
        { int Sb = tot - base;        int Sb1 = Sb - v0; if (Sb >= need && Sb1 < need) { bselS = b2;     bneedS = need - Sb1; } }
        { int Sb = tot - (base + v0); int Sb1 = Sb - v1; if (Sb >= need && Sb1 < need) { bselS = b2 + 1; bneedS = need - Sb1; } }
        __syncthreads();
        if (lv == 0)      prefix = (unsigned)bselS;
        else if (lv == 1) prefix = (prefix << 11) | (unsigned)bselS;
        else              prefix = (prefix << 10) | (unsigned)bselS;
        need = bneedS;
        __syncthreads();
    }
    unsigned T = prefix;
    int greaterCnt = KSEL - need;
    // ---- P4: deterministic perm/newL (rank by index order — identical across blocks)
    {
        int b2 = tid * 2;
        int f0 = skL[b2] > T ? 1 : 0, f1 = skL[b2 + 1] > T ? 1 : 0;
        int s = f0 + f1;
        int incl = wave_incl_scan(s);
        if ((tid & 63) == 63) wsumL[wid] = incl;
        __syncthreads();
        if (tid == 0) {
            int a = 0;
#pragma unroll
            for (int w = 0; w < 16; w++) { int t = wsumL[w]; wsumL[w] = a; a += t; }
        }
        __syncthreads();
        int base = wsumL[wid] + incl - s;
        if (f0) { permL[base] = (unsigned short)b2;       newLs[b2] = (unsigned short)base; }
        if (f1) { int r = base + f0; permL[r] = (unsigned short)(b2 + 1); newLs[b2 + 1] = (unsigned short)r; }
    }
    __syncthreads();
    {   // ties == T: lowest indices first
        int b2 = tid * 2;
        int lc = 0, loc2[2];
#pragma unroll
        for (int k = 0; k < 2; k++)
            if (skL[b2 + k] == T) loc2[lc++] = b2 + k;
        __syncthreads();
        int incl = wave_incl_scan(lc);
        if ((tid & 63) == 63) wsumL[wid] = incl;
        __syncthreads();
        if (tid == 0) {
            int a = 0;
#pragma unroll
            for (int w = 0; w < 16; w++) { int t = wsumL[w]; wsumL[w] = a; a += t; }
        }
        __syncthreads();
        int rank0 = wsumL[wid] + incl - lc;
        for (int j = 0; j < lc; j++) {
            int rank = rank0 + j;
            if (rank < need) {
                int p = greaterCnt + rank;
                permL[p] = (unsigned short)loc2[j];
                newLs[loc2[j]] = (unsigned short)p;
            }
        }
    }
    __syncthreads();
    // ---- P5: gated xp staging (all 410, redundant); zero slice fcnt
    for (int p = tid; p < KSEL; p += 1024) {
        int iL = permL[p];
        unsigned k = skL[iL];
        unsigned u = (k & 0x80000000u) ? (k & 0x7FFFFFFFu) : ~k;
        float tt = tanhf(__uint_as_float(u));
        const float4* xr = (const float4*)(x1g + (size_t)(nbase + iL) * RP);
        float4 q0 = xr[0], q1 = xr[1], q2 = xr[2];
        float* xp = xpL + p * 10;
        xp[0] = q0.x * tt; xp[1] = q0.y * tt; xp[2] = q0.z * tt; xp[3] = q0.w * tt;
        xp[4] = q1.x * tt; xp[5] = q1.y * tt; xp[6] = q1.z * tt; xp[7] = q1.w * tt;
        xp[8] = q2.x * tt; xp[9] = q2.y * tt;
    }
    if (tid < PS) fcntO[tid] = 0;
    __syncthreads();
    // ---- P6: filtered adjacency for OWN p-slice via edge scan
    for (int e = tid; e < EPG; e += 1024) {
        int ee = ebase + e;
        unsigned short s2 = newLs[src[ee] - nbase];
        unsigned short d2 = newLs[dst[ee] - nbase];
        if (s2 != 0xFFFFu && d2 != 0xFFFFu) {
            unsigned pl2 = (unsigned)((int)d2 - ps);
            if (pl2 < (unsigned)PS) {
                int c = atomicAdd(&fcntO[pl2], 1);
                if (c < FCAP) fadjO[pl2 * FCAP + c] = s2;
            }
        }
    }
    __syncthreads();
    // ---- P7: GAT features for ALL kept nodes (redundant, deterministic)
    for (int t = tid; t < KSEL * NH; t += 1024) {
        int p = t / NH, hh = t - p * NH;
        float xi[10];
#pragma unroll
        for (int k = 0; k < 10; k++) xi[k] = xpL[p * 10 + k];
        float v[NC];
        float as_ = 0.f, ad_ = 0.f;
#pragma unroll
        for (int c = 0; c < NC; c++) {
            int j = hh * NC + c;
            float vv = 0.f;
#pragma unroll
            for (int k = 0; k < 10; k++) vv += xi[k] * Wg[k * HC + j];
            v[c] = vv;
            as_ += vv * a_srcw[j];
            ad_ += vv * a_dstw[j];
        }
        float4* hr = (float4*)(hfL + p * HC + hh * NC);
#pragma unroll
        for (int qq = 0; qq < 5; qq++)
            hr[qq] = make_float4(v[4 * qq], v[4 * qq + 1], v[4 * qq + 2], v[4 * qq + 3]);
        alsL[p * NH + hh] = as_;
        aldL[p * NH + hh] = ad_;
    }
    __syncthreads();
    // ---- P8: softmax agg for own slice; butterfly over 64-wide p-groups (round-1 grouping)
    if (tid < NH * PS) {
        float res[NC];
        int hh = tid >> 7;              // 0..2
        int pl = tid & (PS - 1);
        int p = ps + pl;
        if (p < KSEL) {
            float aldp = aldL[p * NH + hh];
            float lself = leaky(alsL[p * NH + hh] + aldp);
            float m = lself;
            int c = fcntO[pl]; if (c > FCAP) c = FCAP;
            const unsigned short* f = fadjO + pl * FCAP;
            for (int e = 0; e < c; e++)
                m = fmaxf(m, leaky(alsL[f[e] * NH + hh] + aldp));
            float wself = expf(lself - m), wsum = wself;
            const float4* hp = (const float4*)(hfL + p * HC + hh * NC);
            float4 r0 = hp[0], r1 = hp[1], r2 = hp[2], r3 = hp[3], r4 = hp[4];
            r0.x *= wself; r0.y *= wself; r0.z *= wself; r0.w *= wself;
            r1.x *= wself; r1.y *= wself; r1.z *= wself; r1.w *= wself;
            r2.x *= wself; r2.y *= wself; r2.z *= wself; r2.w *= wself;
            r3.x *= wself; r3.y *= wself; r3.z *= wself; r3.w *= wself;
            r4.x *= wself; r4.y *= wself; r4.z *= wself; r4.w *= wself;
            for (int e = 0; e < c; e++) {
                int s2 = f[e];
                float w = expf(leaky(alsL[s2 * NH + hh] + aldp) - m);
                wsum += w;
                const float4* hq = (const float4*)(hfL + s2 * HC + hh * NC);
                float4 t0 = hq[0], t1 = hq[1], t2 = hq[2], t3 = hq[3], t4 = hq[4];
                r0.x += w * t0.x; r0.y += w * t0.y; r0.z += w * t0.z; r0.w += w * t0.w;
                r1.x += w * t1.x; r1.y += w * t1.y; r1.z += w * t1.z; r1.w += w * t1.w;
                r2.x += w * t2.x; r2.y += w * t2.y; r2.z += w * t2.z; r2.w += w * t2.w;
                r3.x += w * t3.x; r3.y += w * t3.y; r3.z += w * t3.z; r3.w += w * t3.w;
                r4.x += w * t4.x; r4.y += w * t4.y; r4.z += w * t4.z; r4.w += w * t4.w;
            }
            float inv = 1.f / wsum;
            res[0] = r0.x * inv;  res[1] = r0.y * inv;  res[2] = r0.z * inv;  res[3] = r0.w * inv;
            res[4] = r1.x * inv;  res[5] = r1.y * inv;  res[6] = r1.z * inv;  res[7] = r1.w * inv;
            res[8] = r2.x * inv;  res[9] = r2.y * inv;  res[10] = r2.z * inv; res[11] = r2.w * inv;
            res[12] = r3.x * inv; res[13] = r3.y * inv; res[14] = r3.z * inv; res[15] = r3.w * inv;
            res[16] = r4.x * inv; res[17] = r4.y * inv; res[18] = r4.z * inv; res[19] = r4.w * inv;
        } else {
#pragma unroll
            for (int cc = 0; cc < NC; cc++) res[cc] = 0.f;
        }
#pragma unroll
        for (int cc = 0; cc < NC; cc++) {
            float v = res[cc];
#pragma unroll
            for (int d = 1; d < 64; d <<= 1) v += __shfl_xor(v, d, 64);
            res[cc] = v;
        }
        if ((tid & 63) == 0) {
            int gl = 2 * q + ((tid >> 6) & 1);          // p-group index 0..7
            float* gp = gpart + ((size_t)g * 24 + (hh * 8 + gl)) * NC;
#pragma unroll
            for (int cc = 0; cc < NC; cc++) gp[cc] = res[cc];
        }
    }
    // ---- P9: last-block-does-tail (no spinning)
    __threadfence();
    __syncthreads();
    if (tid == 0) {
        int old = atomicAdd(&tick[g], 1);
        lastS = ((old & 3) == 3) ? 1 : 0;
    }
    __syncthreads();
    if (lastS) {
        __threadfence();   // acquire: see other blocks' gpart writes
        if (tid < HC) {
            int hh = tid / NC, c = tid - hh * NC;
            float a = 0.f;
#pragma unroll
            for (int w = 0; w < 8; w++)
                a += gpart[((size_t)g * 24 + hh * 8 + w) * NC + c];
            goutL[tid] = a + (float)KSEL * bg[tid];
        }
        __syncthreads();
        if (tid < 30) {
            float s = bf1[tid];
#pragma unroll
            for (int k = 0; k < HC; k++) s += goutL[k] * Wf1[k * 30 + tid];
            hidL[tid] = s > 0.f ? s : 0.f;
        }
        __syncthreads();
        if (tid == 0) {
            float z[3];
#pragma unroll
            for (int j = 0; j < 3; j++) {
                float s = bf2[j];
                for (int k = 0; k < 30; k++) s += hidL[k] * Wf2[k * 3 + j];
                z[j] = s;
            }
            float m = fmaxf(z[0], fmaxf(z[1], z[2]));
            float lse = logf(expf(z[0] - m) + expf(z[1] - m) + expf(z[2] - m)) + m;
#pragma unroll
            for (int j = 0; j < 3; j++) out[g * 3 + j] = z[j] - lse;
        }
    }
}

extern "C" void kernel_launch(void* const* d_in, const int* in_sizes, int n_in,
                              void* d_out, int out_size, void* d_ws, size_t ws_size,
                              hipStream_t stream) {
    const float* x     = (const float*)d_in[0];
    const int*   src   = (const int*)d_in[1];
    const int*   dst   = (const int*)d_in[2];
    const float* W1    = (const float*)d_in[4];
    const float* b1    = (const float*)d_in[5];
    const float* Ws    = (const float*)d_in[6];
    const float* bs    = (const float*)d_in[7];
    const float* Wg    = (const float*)d_in[8];
    const float* a_src = (const float*)d_in[9];
    const float* a_dst = (const float*)d_in[10];
    const float* bg    = (const float*)d_in[11];
    const float* Wf1   = (const float*)d_in[12];
    const float* bf1   = (const float*)d_in[13];
    const float* Wf2   = (const float*)d_in[14];
    const float* bf2   = (const float*)d_in[15];
    float* out = (float*)d_out;

    // ws layout: x1g @0 (6291456 B) | tick @6291456 (256 B) | gpart @6291712 (122880 B)
    float* x1g   = (float*)d_ws;
    int*   tick  = (int*)((char*)d_ws + 6291456);
    float* gpart = (float*)((char*)d_ws + 6291712);

    hipMemsetAsync((char*)d_ws + 6291456, 0, 256, stream);
    k1_gcn<<<G * 4, 1024, 0, stream>>>(x, src, dst, W1, b1, Ws, x1g);
    k2_wide<<<G * 4, 1024, 0, stream>>>(src, dst, bs, Wg, a_src, a_dst, bg,
                                        Wf1, bf1, Wf2, bf2, x1g, gpart, tick, out);
}

// Round 4
// 143.716 us; speedup vs baseline: 1.6323x; 1.6323x over previous
//
#include <hip/hip_runtime.h>
#include <math.h>

#define G    64
#define NPG  2048
#define NTOT (G * NPG)          // 131072
#define EPG  (NPG * 8)          // 16384 edges per graph
#define KSEL 410
#define NH   3
#define NC   20
#define HC   60
#define FCAP 24
#define KPAD 512
#define RP   12                 // h1p padded row: h1/x1[0..9], dinv@10, hs@11 (48 B)

// ---- LDS arena (bytes). Phases: A csr+h1, B gcn10(in-place x1), C scorer,
//      D topk, E2 xp-stage, E1 fadj, F gat feat, G agg+readout, H mlp.
// x1 now lives in h1p (in-place) until E2; xp/fadj/fcnt relocated into the
// h1p head, which dies at E2 (reg-staged copy covers the RAW/WAR hazard).
#define OFF_H1P   0             // 98304  h1p 2048x12f            [A..E2]
#define OFF_XP    0             // 16400  xp 410x10f              [E2..F]  (h1p head dead)
#define OFF_FADJ  16400         // 19680  fadj 410x24 u16         [E1..G]  (h1p dead)
#define OFF_FCNT  36080         // 1648   fcnt int                [E1..G]
#define OFF_HF    37728         // 98400  hf 410x60f              [F..G]   (h1p/csr/hist dead)
#define OFF_CSR   98304         // 32768  csr u16                 [A..E1]
#define OFF_HIST  131072        // 8192   hist/bins int           [A..D]
#define OFF_RS    139264        // 8192   rs int                  [A..E1]
#define OFF_ALS   139264        // 4920   als                     [F..G]   (rs dead)
#define OFF_ALD   144184        // 4920   ald                     [F..G]
#define OFF_SK    147456        // 8192   sk u32                  [C..E2]
#define OFF_WRED  149104        // 1920   [G]                     (sk dead)
#define OFF_GOUT  151024        // 240    [G..H]
#define OFF_HID   151264        // 120    [H]
#define OFF_NEWL  155648        // 4096   newL u16                [C..E1]
#define OFF_PERML 159744        // 824    permL u16               [D..E2]
#define OFF_WSUM  160568        // 64
#define OFF_FLAGS 160632        // 16
#define ARENA_SZ  160648

__device__ inline float leaky(float x) { return x >= 0.f ? x : 0.2f * x; }

__device__ inline int wave_incl_scan(int v) {
    int lane = threadIdx.x & 63;
#pragma unroll
    for (int d = 1; d < 64; d <<= 1) {
        int t = __shfl_up(v, d, 64);
        if (lane >= d) v += t;
    }
    return v;
}

__global__ __launch_bounds__(1024) void k_all(
    const float* __restrict__ x, const int* __restrict__ src, const int* __restrict__ dst,
    const float* __restrict__ W1, const float* __restrict__ b1,
    const float* __restrict__ Ws, const float* __restrict__ bs,
    const float* __restrict__ Wg, const float* __restrict__ a_srcw,
    const float* __restrict__ a_dstw, const float* __restrict__ bg,
    const float* __restrict__ Wf1, const float* __restrict__ bf1,
    const float* __restrict__ Wf2, const float* __restrict__ bf2,
    float* __restrict__ out)
{
    __shared__ __align__(16) char arena[ARENA_SZ];
    float*          h1p   = (float*)(arena + OFF_H1P);
    float*          xpL   = (float*)(arena + OFF_XP);
    unsigned short* fadjL = (unsigned short*)(arena + OFF_FADJ);
    int*            fcntL = (int*)(arena + OFF_FCNT);
    float*          hfL   = (float*)(arena + OFF_HF);
    unsigned short* csrL  = (unsigned short*)(arena + OFF_CSR);
    int*            hist  = (int*)(arena + OFF_HIST);
    int*            rsL   = (int*)(arena + OFF_RS);
    float*          alsL  = (float*)(arena + OFF_ALS);
    float*          aldL  = (float*)(arena + OFF_ALD);
    unsigned*       skL   = (unsigned*)(arena + OFF_SK);
    float*          wred  = (float*)(arena + OFF_WRED);
    float*          goutL = (float*)(arena + OFF_GOUT);
    float*          hidL  = (float*)(arena + OFF_HID);
    unsigned short* newLs = (unsigned short*)(arena + OFF_NEWL);
    unsigned short* permL = (unsigned short*)(arena + OFF_PERML);
    int*            wsumL = (int*)(arena + OFF_WSUM);
    int*            flags = (int*)(arena + OFF_FLAGS);
#define bselS  flags[0]
#define bneedS flags[1]
#define curS   flags[2]
#define totS   flags[3]

    int g = blockIdx.x, tid = threadIdx.x, wid = tid >> 6;
    int nbase = g * NPG, ebase = g * EPG;

    // ---- Phase A: zero hist; h1 -> LDS (padded rows, vector writes)
    for (int i = tid; i < NPG; i += 1024) hist[i] = 0;
    for (int i = tid; i < NPG; i += 1024) {
        float xi[5];
#pragma unroll
        for (int k = 0; k < 5; k++) xi[k] = x[(size_t)(nbase + i) * 5 + k];
        float v[10];
#pragma unroll
        for (int j = 0; j < 10; j++) {
            float s = 0.f;
#pragma unroll
            for (int k = 0; k < 5; k++) s += xi[k] * W1[k * 10 + j];
            v[j] = s;
        }
        float4* row = (float4*)(h1p + i * RP);
        row[0] = make_float4(v[0], v[1], v[2], v[3]);
        row[1] = make_float4(v[4], v[5], v[6], v[7]);
        row[2] = make_float4(v[8], v[9], 0.f, 0.f);   // slots 10/11 rewritten later
    }
    __syncthreads();
    for (int e = tid; e < EPG; e += 1024)
        atomicAdd(&hist[dst[ebase + e] - nbase], 1);
    __syncthreads();
    {   // exclusive scan (2 bins/thread, 16 wave partials); dinv -> row slot 10
        int b2 = tid * 2;
        int v0 = hist[b2], v1 = hist[b2 + 1];
        int s = v0 + v1;
        int incl = wave_incl_scan(s);
        if ((tid & 63) == 63) wsumL[wid] = incl;
        __syncthreads();
        if (tid == 0) {
            int a = 0;
#pragma unroll
            for (int w = 0; w < 16; w++) { int t = wsumL[w]; wsumL[w] = a; a += t; }
        }
        __syncthreads();
        int base = wsumL[wid] + incl - s;
        rsL[b2] = base;
        rsL[b2 + 1] = base + v0;
        h1p[b2 * RP + 10] = rsqrtf((float)v0 + 1.0f);
        h1p[(b2 + 1) * RP + 10] = rsqrtf((float)v1 + 1.0f);
        hist[b2] = 0; hist[b2 + 1] = 0;              // cursors
    }
    __syncthreads();
    for (int e = tid; e < EPG; e += 1024) {
        int ee = ebase + e;
        int sl = src[ee] - nbase;
        int dl = dst[ee] - nbase;
        int pos = rsL[dl] + atomicAdd(&hist[dl], 1);
        csrL[pos] = (unsigned short)sl;
    }
    __syncthreads();

    // ---- Phase B: GCN10 gather, DUAL-node interleaved chains; x1 written IN PLACE
    {
        int i0 = tid, i1 = tid + 1024;
        int e0 = rsL[i0], e0e = rsL[i0 + 1];
        int e1 = rsL[i1], e1e = (i1 == NPG - 1) ? EPG : rsL[i1 + 1];
        float acc0[10], acc1[10];
#pragma unroll
        for (int j = 0; j < 10; j++) { acc0[j] = 0.f; acc1[j] = 0.f; }
        while (e0 < e0e || e1 < e1e) {
            if (e0 < e0e) {
                int s = csrL[e0++];
                const float4* rw = (const float4*)(h1p + s * RP);
                float4 r0 = rw[0], r1 = rw[1], r2 = rw[2];
                float dv = r2.z;
                acc0[0] += r0.x * dv; acc0[1] += r0.y * dv; acc0[2] += r0.z * dv; acc0[3] += r0.w * dv;
                acc0[4] += r1.x * dv; acc0[5] += r1.y * dv; acc0[6] += r1.z * dv; acc0[7] += r1.w * dv;
                acc0[8] += r2.x * dv; acc0[9] += r2.y * dv;
            }
            if (e1 < e1e) {
                int s = csrL[e1++];
                const float4* rw = (const float4*)(h1p + s * RP);
                float4 r0 = rw[0], r1 = rw[1], r2 = rw[2];
                float dv = r2.z;
                acc1[0] += r0.x * dv; acc1[1] += r0.y * dv; acc1[2] += r0.z * dv; acc1[3] += r0.w * dv;
                acc1[4] += r1.x * dv; acc1[5] += r1.y * dv; acc1[6] += r1.z * dv; acc1[7] += r1.w * dv;
                acc1[8] += r2.x * dv; acc1[9] += r2.y * dv;
            }
        }
        const float4* q0 = (const float4*)(h1p + i0 * RP);
        const float4* q1 = (const float4*)(h1p + i1 * RP);
        float4 s00 = q0[0], s01 = q0[1], s02 = q0[2];
        float4 s10 = q1[0], s11 = q1[1], s12 = q1[2];
        float di0 = s02.z, d20 = di0 * di0;
        float di1 = s12.z, d21 = di1 * di1;
        float b1r[10];
#pragma unroll
        for (int j = 0; j < 10; j++) b1r[j] = b1[j];
        float v0[10], v1[10];
        v0[0] = acc0[0] * di0 + s00.x * d20 + b1r[0];
        v0[1] = acc0[1] * di0 + s00.y * d20 + b1r[1];
        v0[2] = acc0[2] * di0 + s00.z * d20 + b1r[2];
        v0[3] = acc0[3] * di0 + s00.w * d20 + b1r[3];
        v0[4] = acc0[4] * di0 + s01.x * d20 + b1r[4];
        v0[5] = acc0[5] * di0 + s01.y * d20 + b1r[5];
        v0[6] = acc0[6] * di0 + s01.z * d20 + b1r[6];
        v0[7] = acc0[7] * di0 + s01.w * d20 + b1r[7];
        v0[8] = acc0[8] * di0 + s02.x * d20 + b1r[8];
        v0[9] = acc0[9] * di0 + s02.y * d20 + b1r[9];
        v1[0] = acc1[0] * di1 + s10.x * d21 + b1r[0];
        v1[1] = acc1[1] * di1 + s10.y * d21 + b1r[1];
        v1[2] = acc1[2] * di1 + s10.z * d21 + b1r[2];
        v1[3] = acc1[3] * di1 + s10.w * d21 + b1r[3];
        v1[4] = acc1[4] * di1 + s11.x * d21 + b1r[4];
        v1[5] = acc1[5] * di1 + s11.y * d21 + b1r[5];
        v1[6] = acc1[6] * di1 + s11.z * d21 + b1r[6];
        v1[7] = acc1[7] * di1 + s11.w * d21 + b1r[7];
        v1[8] = acc1[8] * di1 + s12.x * d21 + b1r[8];
        v1[9] = acc1[9] * di1 + s12.y * d21 + b1r[9];
        float hs0 = 0.f, hs1 = 0.f;
#pragma unroll
        for (int j = 0; j < 10; j++) { float w = Ws[j]; hs0 += v0[j] * w; hs1 += v1[j] * w; }
        __syncthreads();   // all gathers complete before any in-place overwrite
        float4* w0 = (float4*)(h1p + i0 * RP);
        w0[0] = make_float4(v0[0], v0[1], v0[2], v0[3]);
        w0[1] = make_float4(v0[4], v0[5], v0[6], v0[7]);
        w0[2] = make_float4(v0[8], v0[9], di0, hs0);
        float4* w1 = (float4*)(h1p + i1 * RP);
        w1[0] = make_float4(v1[0], v1[1], v1[2], v1[3]);
        w1[1] = make_float4(v1[4], v1[5], v1[6], v1[7]);
        w1[2] = make_float4(v1[8], v1[9], di1, hs1);
    }
    __syncthreads();

    // ---- Phase C: scorer gather ((dinv,hs) b64), DUAL-node interleaved; keys; init topk
    {
        float bsv = bs[0];
        int i0 = tid, i1 = tid + 1024;
        float2 own0 = *(const float2*)(h1p + i0 * RP + 10);
        float2 own1 = *(const float2*)(h1p + i1 * RP + 10);
        int e0 = rsL[i0], e0e = rsL[i0 + 1];
        int e1 = rsL[i1], e1e = (i1 == NPG - 1) ? EPG : rsL[i1 + 1];
        float a0 = 0.f, a1 = 0.f;
        while (e0 < e0e || e1 < e1e) {
            if (e0 < e0e) { float2 dh = *(const float2*)(h1p + csrL[e0++] * RP + 10); a0 += dh.x * dh.y; }
            if (e1 < e1e) { float2 dh = *(const float2*)(h1p + csrL[e1++] * RP + 10); a1 += dh.x * dh.y; }
        }
        float sc0 = own0.x * a0 + own0.y * own0.x * own0.x + bsv;
        float sc1 = own1.x * a1 + own1.y * own1.x * own1.x + bsv;
        unsigned u0 = __float_as_uint(sc0);
        unsigned u1 = __float_as_uint(sc1);
        skL[i0] = (u0 & 0x80000000u) ? ~u0 : (u0 | 0x80000000u);
        skL[i1] = (u1 & 0x80000000u) ? ~u1 : (u1 | 0x80000000u);
        newLs[i0] = 0xFFFFu; newLs[i1] = 0xFFFFu;
        hist[i0] = 0; hist[i1] = 0;
    }
    if (tid == 0) curS = 0;
    int need = KSEL;
    unsigned prefix = 0;
    __syncthreads();

    // ---- Phase D: 3-level radix select (11/11/10 bits)
    for (int lv = 0; lv < 3; lv++) {
        for (int i = tid; i < NPG; i += 1024) {
            unsigned k = skL[i];
            bool match; unsigned bb;
            if (lv == 0)      { match = true;                  bb = k >> 21; }
            else if (lv == 1) { match = ((k >> 21) == prefix); bb = (k >> 10) & 0x7FFu; }
            else              { match = ((k >> 10) == prefix); bb = k & 0x3FFu; }
            if (match) atomicAdd(&hist[bb], 1);
        }
        __syncthreads();
        int b2 = tid * 2;
        int v0 = hist[b2], v1 = hist[b2 + 1];
        hist[b2] = 0; hist[b2 + 1] = 0;
        int s = v0 + v1;
        int incl = wave_incl_scan(s);
        if ((tid & 63) == 63) wsumL[wid] = incl;
        __syncthreads();
        if (tid == 0) {
            int a = 0;
#pragma unroll
            for (int w = 0; w < 16; w++) { int t = wsumL[w]; wsumL[w] = a; a += t; }
            totS = a;
        }
        __syncthreads();
        int base = wsumL[wid] + incl - s;
        int tot = totS;
        { int Sb = tot - base;        int Sb1 = Sb - v0; if (Sb >= need && Sb1 < need) { bselS = b2;     bneedS = need - Sb1; } }
        { int Sb = tot - (base + v0); int Sb1 = Sb - v1; if (Sb >= need && Sb1 < need) { bselS = b2 + 1; bneedS = need - Sb1; } }
        __syncthreads();
        if (lv == 0)      prefix = (unsigned)bselS;
        else if (lv == 1) prefix = (prefix << 11) | (unsigned)bselS;
        else              prefix = (prefix << 10) | (unsigned)bselS;
        need = bneedS;
        __syncthreads();
    }
    unsigned T = prefix;              // exact K-th largest key; need = #ties to take
    int greaterCnt = KSEL - need;

    for (int i = tid; i < NPG; i += 1024) {
        if (skL[i] > T) {
            int p = atomicAdd(&curS, 1);
            permL[p] = (unsigned short)i;
            newLs[i] = (unsigned short)p;
        }
    }
    {   // ties == T: lowest indices first
        int b2 = tid * 2;
        int lc = 0, loc2[2];
#pragma unroll
        for (int k = 0; k < 2; k++)
            if (skL[b2 + k] == T) loc2[lc++] = b2 + k;
        __syncthreads();
        int incl = wave_incl_scan(lc);
        if ((tid & 63) == 63) wsumL[wid] = incl;
        __syncthreads();
        if (tid == 0) {
            int a = 0;
#pragma unroll
            for (int w = 0; w < 16; w++) { int t = wsumL[w]; wsumL[w] = a; a += t; }
        }
        __syncthreads();
        int rank0 = wsumL[wid] + incl - lc;
        for (int j = 0; j < lc; j++) {
            int rank = rank0 + j;
            if (rank < need) {
                int p = greaterCnt + rank;
                permL[p] = (unsigned short)loc2[j];
                newLs[loc2[j]] = (unsigned short)p;
            }
        }
    }
    __syncthreads();

    // ---- Phase E2: gated pooled features, reg-staged (x1 from LDS), then xp over h1p head
    {
        float4 rq0, rq1, rq2; float tt = 0.f;
        bool havep = (tid < KSEL);
        if (havep) {
            int iL = permL[tid];
            unsigned k = skL[iL];
            unsigned u = (k & 0x80000000u) ? (k & 0x7FFFFFFFu) : ~k;
            tt = tanhf(__uint_as_float(u));
            const float4* xr = (const float4*)(h1p + iL * RP);
            rq0 = xr[0]; rq1 = xr[1]; rq2 = xr[2];
        }
        __syncthreads();   // all x1 reads complete before xp overwrites h1p head
        if (havep) {
            float* xp = xpL + tid * 10;
            xp[0] = rq0.x * tt; xp[1] = rq0.y * tt; xp[2] = rq0.z * tt; xp[3] = rq0.w * tt;
            xp[4] = rq1.x * tt; xp[5] = rq1.y * tt; xp[6] = rq1.z * tt; xp[7] = rq1.w * tt;
            xp[8] = rq2.x * tt; xp[9] = rq2.y * tt;
        }
    }
    __syncthreads();

    // ---- Phase E1: filtered adjacency from CSR (csr/rs/newL still live)
    for (int p = tid; p < KSEL; p += 1024) {
        int iL = permL[p];
        int p0 = rsL[iL], p1 = (iL == NPG - 1) ? EPG : rsL[iL + 1];
        int c = 0;
        for (int e = p0; e < p1; e++) {
            unsigned short s2 = newLs[csrL[e]];
            if (s2 != 0xFFFFu && c < FCAP) fadjL[p * FCAP + c++] = s2;
        }
        fcntL[p] = c;
    }
    __syncthreads();

    // ---- Phase F: GAT features per (p, head)
    for (int t = tid; t < KSEL * NH; t += 1024) {
        int p = t / NH, hh = t - p * NH;
        float xi[10];
#pragma unroll
        for (int k = 0; k < 10; k++) xi[k] = xpL[p * 10 + k];
        float v[NC];
        float as_ = 0.f, ad_ = 0.f;
#pragma unroll
        for (int c = 0; c < NC; c++) {
            int j = hh * NC + c;
            float vv = 0.f;
#pragma unroll
            for (int k = 0; k < 10; k++) vv += xi[k] * Wg[k * HC + j];
            v[c] = vv;
            as_ += vv * a_srcw[j];
            ad_ += vv * a_dstw[j];
        }
        float4* hr = (float4*)(hfL + p * HC + hh * NC);
#pragma unroll
        for (int q = 0; q < 5; q++)
            hr[q] = make_float4(v[4 * q], v[4 * q + 1], v[4 * q + 2], v[4 * q + 3]);
        alsL[p * NH + hh] = as_;
        aldL[p * NH + hh] = ad_;
    }
    __syncthreads();

    // ---- Phase G: softmax agg over filtered adjacency + butterfly readout
    {
        float res[NC];
#pragma unroll
        for (int rnd = 0; rnd < 2; rnd++) {
            int task = rnd == 0 ? tid : 1024 + tid;
            bool on = rnd == 0 || tid < KPAD;
            int hh = task >> 9, p = task & (KPAD - 1);
            if (on) {
                if (p < KSEL) {
                    float aldp = aldL[p * NH + hh];
                    float lself = leaky(alsL[p * NH + hh] + aldp);
                    float m = lself;
                    int c = fcntL[p];
                    const unsigned short* f = fadjL + p * FCAP;
                    for (int e = 0; e < c; e++)
                        m = fmaxf(m, leaky(alsL[f[e] * NH + hh] + aldp));
                    float wself = expf(lself - m), wsum = wself;
                    const float4* hp = (const float4*)(hfL + p * HC + hh * NC);
                    float4 r0 = hp[0], r1 = hp[1], r2 = hp[2], r3 = hp[3], r4 = hp[4];
                    r0.x *= wself; r0.y *= wself; r0.z *= wself; r0.w *= wself;
                    r1.x *= wself; r1.y *= wself; r1.z *= wself; r1.w *= wself;
                    r2.x *= wself; r2.y *= wself; r2.z *= wself; r2.w *= wself;
                    r3.x *= wself; r3.y *= wself; r3.z *= wself; r3.w *= wself;
                    r4.x *= wself; r4.y *= wself; r4.z *= wself; r4.w *= wself;
                    for (int e = 0; e < c; e++) {
                        int s2 = f[e];
                        float w = expf(leaky(alsL[s2 * NH + hh] + aldp) - m);
                        wsum += w;
                        const float4* hq = (const float4*)(hfL + s2 * HC + hh * NC);
                        float4 t0 = hq[0], t1 = hq[1], t2 = hq[2], t3 = hq[3], t4 = hq[4];
                        r0.x += w * t0.x; r0.y += w * t0.y; r0.z += w * t0.z; r0.w += w * t0.w;
                        r1.x += w * t1.x; r1.y += w * t1.y; r1.z += w * t1.z; r1.w += w * t1.w;
                        r2.x += w * t2.x; r2.y += w * t2.y; r2.z += w * t2.z; r2.w += w * t2.w;
                        r3.x += w * t3.x; r3.y += w * t3.y; r3.z += w * t3.z; r3.w += w * t3.w;
                        r4.x += w * t4.x; r4.y += w * t4.y; r4.z += w * t4.z; r4.w += w * t4.w;
                    }
                    float inv = 1.f / wsum;
                    res[0] = r0.x * inv;  res[1] = r0.y * inv;  res[2] = r0.z * inv;  res[3] = r0.w * inv;
                    res[4] = r1.x * inv;  res[5] = r1.y * inv;  res[6] = r1.z * inv;  res[7] = r1.w * inv;
                    res[8] = r2.x * inv;  res[9] = r2.y * inv;  res[10] = r2.z * inv; res[11] = r2.w * inv;
                    res[12] = r3.x * inv; res[13] = r3.y * inv; res[14] = r3.z * inv; res[15] = r3.w * inv;
                    res[16] = r4.x * inv; res[17] = r4.y * inv; res[18] = r4.z * inv; res[19] = r4.w * inv;
                } else {
#pragma unroll
                    for (int cc = 0; cc < NC; cc++) res[cc] = 0.f;
                }
#pragma unroll
                for (int cc = 0; cc < NC; cc++) {
                    float v = res[cc];
#pragma unroll
                    for (int d = 1; d < 64; d <<= 1) v += __shfl_xor(v, d, 64);
                    res[cc] = v;
                }
                if ((tid & 63) == 0) {
                    int slot = rnd == 0 ? hh * 8 + (wid & 7) : 16 + wid;
#pragma unroll
                    for (int cc = 0; cc < NC; cc++) wred[slot * NC + cc] = res[cc];
                }
            }
        }
    }
    __syncthreads();
    if (tid < HC) {
        int hh = tid / NC, c = tid - hh * NC;
        float a = 0.f;
#pragma unroll
        for (int w = 0; w < 8; w++) a += wred[(hh * 8 + w) * NC + c];
        goutL[tid] = a + (float)KSEL * bg[tid];
    }
    __syncthreads();

    // ---- Phase H: MLP + log_softmax
    if (tid < 30) {
        float s = bf1[tid];
#pragma unroll
        for (int k = 0; k < HC; k++) s += goutL[k] * Wf1[k * 30 + tid];
        hidL[tid] = s > 0.f ? s : 0.f;
    }
    __syncthreads();
    if (tid == 0) {
        float z[3];
#pragma unroll
        for (int j = 0; j < 3; j++) {
            float s = bf2[j];
            for (int k = 0; k < 30; k++) s += hidL[k] * Wf2[k * 3 + j];
            z[j] = s;
        }
        float m = fmaxf(z[0], fmaxf(z[1], z[2]));
        float lse = logf(expf(z[0] - m) + expf(z[1] - m) + expf(z[2] - m)) + m;
#pragma unroll
        for (int j = 0; j < 3; j++) out[g * 3 + j] = z[j] - lse;
    }
}

extern "C" void kernel_launch(void* const* d_in, const int* in_sizes, int n_in,
                              void* d_out, int out_size, void* d_ws, size_t ws_size,
                              hipStream_t stream) {
    const float* x     = (const float*)d_in[0];
    const int*   src   = (const int*)d_in[1];
    const int*   dst   = (const int*)d_in[2];
    const float* W1    = (const float*)d_in[4];
    const float* b1    = (const float*)d_in[5];
    const float* Ws    = (const float*)d_in[6];
    const float* bs    = (const float*)d_in[7];
    const float* Wg    = (const float*)d_in[8];
    const float* a_src = (const float*)d_in[9];
    const float* a_dst = (const float*)d_in[10];
    const float* bg    = (const float*)d_in[11];
    const float* Wf1   = (const float*)d_in[12];
    const float* bf1   = (const float*)d_in[13];
    const float* Wf2   = (const float*)d_in[14];
    const float* bf2   = (const float*)d_in[15];
    float* out = (float*)d_out;
    (void)d_ws; (void)ws_size;   // no workspace: x1 stays in LDS

    k_all<<<G, 1024, 0, stream>>>(x, src, dst, W1, b1, Ws, bs, Wg, a_src, a_dst,
                                  bg, Wf1, bf1, Wf2, bf2, out);
}

// Round 5
// 141.391 us; speedup vs baseline: 1.6591x; 1.0164x over previous
//
#include <hip/hip_runtime.h>
#include <math.h>

#define G    64
#define NPG  2048
#define NTOT (G * NPG)          // 131072
#define EPG  (NPG * 8)          // 16384 edges per graph
#define KSEL 410
#define NH   3
#define NC   20
#define HC   60
#define FCAP 24
#define KPAD 512
#define RP   12                 // h1p padded row: h1/x1[0..9], dinv@10, hs@11 (48 B)

// ---- LDS arena (bytes). Phases: A csr+h1, B gcn10(in-place x1), C scorer,
//      D topk, E2 xp-stage, E1 fadj, F gat feat, G agg+readout, H mlp.
#define OFF_H1P   0             // 98304  h1p 2048x12f            [A..E2]
#define OFF_XP    0             // 16400  xp 410x10f              [E2..F]  (h1p head dead)
#define OFF_FADJ  16400         // 19680  fadj 410x24 u16         [E1..G]  (h1p dead)
#define OFF_FCNT  36080         // 1648   fcnt int                [E1..G]
#define OFF_HF    37728         // 98400  hf 410x60f              [F..G]   (h1p/csr/hist dead)
#define OFF_CSR   98304         // 32768  csr u16                 [A..E1]
#define OFF_HIST  131072        // 8192   hist/bins int           [A..D]
#define OFF_RS    139264        // 8192   rs int                  [A..E1]
#define OFF_ALS   139264        // 4920   als                     [F..G]   (rs dead)
#define OFF_ALD   144184        // 4920   ald                     [F..G]
#define OFF_SK    147456        // 8192   sk u32                  [C..E2]
#define OFF_WRED  149104        // 1920   [G]                     (sk dead)
#define OFF_GOUT  151024        // 240    [G..H]
#define OFF_HID   151264        // 120    [H]
#define OFF_NEWL  155648        // 4096   newL u16                [C..E1]
#define OFF_PERML 159744        // 824    permL u16               [D..E2]
#define OFF_WSUM  160568        // 64
#define OFF_FLAGS 160632        // 16
#define ARENA_SZ  160648

__device__ inline float leaky(float x) { return x >= 0.f ? x : 0.2f * x; }

__device__ inline int wave_incl_scan(int v) {
    int lane = threadIdx.x & 63;
#pragma unroll
    for (int d = 1; d < 64; d <<= 1) {
        int t = __shfl_up(v, d, 64);
        if (lane >= d) v += t;
    }
    return v;
}

__global__ __launch_bounds__(1024) void k_all(
    const float* __restrict__ x, const int* __restrict__ src, const int* __restrict__ dst,
    const float* __restrict__ W1, const float* __restrict__ b1,
    const float* __restrict__ Ws, const float* __restrict__ bs,
    const float* __restrict__ Wg, const float* __restrict__ a_srcw,
    const float* __restrict__ a_dstw, const float* __restrict__ bg,
    const float* __restrict__ Wf1, const float* __restrict__ bf1,
    const float* __restrict__ Wf2, const float* __restrict__ bf2,
    float* __restrict__ out)
{
    __shared__ __align__(16) char arena[ARENA_SZ];
    float*          h1p   = (float*)(arena + OFF_H1P);
    float*          xpL   = (float*)(arena + OFF_XP);
    unsigned short* fadjL = (unsigned short*)(arena + OFF_FADJ);
    int*            fcntL = (int*)(arena + OFF_FCNT);
    float*          hfL   = (float*)(arena + OFF_HF);
    unsigned short* csrL  = (unsigned short*)(arena + OFF_CSR);
    int*            hist  = (int*)(arena + OFF_HIST);
    int*            rsL   = (int*)(arena + OFF_RS);
    float*          alsL  = (float*)(arena + OFF_ALS);
    float*          aldL  = (float*)(arena + OFF_ALD);
    unsigned*       skL   = (unsigned*)(arena + OFF_SK);
    float*          wred  = (float*)(arena + OFF_WRED);
    float*          goutL = (float*)(arena + OFF_GOUT);
    float*          hidL  = (float*)(arena + OFF_HID);
    unsigned short* newLs = (unsigned short*)(arena + OFF_NEWL);
    unsigned short* permL = (unsigned short*)(arena + OFF_PERML);
    int*            wsumL = (int*)(arena + OFF_WSUM);
    int*            flags = (int*)(arena + OFF_FLAGS);
#define bselS  flags[0]
#define bneedS flags[1]
#define totS   flags[3]

    int g = blockIdx.x, tid = threadIdx.x, wid = tid >> 6;
    int nbase = g * NPG, ebase = g * EPG;

    // ---- Phase A: zero hist; h1 -> LDS (padded rows, vector writes)
    for (int i = tid; i < NPG; i += 1024) hist[i] = 0;
    for (int i = tid; i < NPG; i += 1024) {
        float xi[5];
#pragma unroll
        for (int k = 0; k < 5; k++) xi[k] = x[(size_t)(nbase + i) * 5 + k];
        float v[10];
#pragma unroll
        for (int j = 0; j < 10; j++) {
            float s = 0.f;
#pragma unroll
            for (int k = 0; k < 5; k++) s += xi[k] * W1[k * 10 + j];
            v[j] = s;
        }
        float4* row = (float4*)(h1p + i * RP);
        row[0] = make_float4(v[0], v[1], v[2], v[3]);
        row[1] = make_float4(v[4], v[5], v[6], v[7]);
        row[2] = make_float4(v[8], v[9], 0.f, 0.f);   // slots 10/11 rewritten later
    }
    __syncthreads();
    for (int e = tid; e < EPG; e += 1024)
        atomicAdd(&hist[dst[ebase + e] - nbase], 1);
    __syncthreads();
    {   // exclusive scan (2 bins/thread, 16 wave partials); dinv -> row slot 10
        int b2 = tid * 2;
        int v0 = hist[b2], v1 = hist[b2 + 1];
        int s = v0 + v1;
        int incl = wave_incl_scan(s);
        if ((tid & 63) == 63) wsumL[wid] = incl;
        __syncthreads();
        if (tid == 0) {
            int a = 0;
#pragma unroll
            for (int w = 0; w < 16; w++) { int t = wsumL[w]; wsumL[w] = a; a += t; }
        }
        __syncthreads();
        int base = wsumL[wid] + incl - s;
        rsL[b2] = base;
        rsL[b2 + 1] = base + v0;
        h1p[b2 * RP + 10] = rsqrtf((float)v0 + 1.0f);
        h1p[(b2 + 1) * RP + 10] = rsqrtf((float)v1 + 1.0f);
        hist[b2] = 0; hist[b2 + 1] = 0;              // cursors
    }
    __syncthreads();
    for (int e = tid; e < EPG; e += 1024) {
        int ee = ebase + e;
        int sl = src[ee] - nbase;
        int dl = dst[ee] - nbase;
        int pos = rsL[dl] + atomicAdd(&hist[dl], 1);
        csrL[pos] = (unsigned short)sl;
    }
    __syncthreads();

    // ---- Phase B: GCN10 gather, dual-node; x1 written IN PLACE (verified round-4)
    {
        int i0 = tid, i1 = tid + 1024;
        int e0 = rsL[i0], e0e = rsL[i0 + 1];
        int e1 = rsL[i1], e1e = (i1 == NPG - 1) ? EPG : rsL[i1 + 1];
        float acc0[10], acc1[10];
#pragma unroll
        for (int j = 0; j < 10; j++) { acc0[j] = 0.f; acc1[j] = 0.f; }
        while (e0 < e0e || e1 < e1e) {
            if (e0 < e0e) {
                int s = csrL[e0++];
                const float4* rw = (const float4*)(h1p + s * RP);
                float4 r0 = rw[0], r1 = rw[1], r2 = rw[2];
                float dv = r2.z;
                acc0[0] += r0.x * dv; acc0[1] += r0.y * dv; acc0[2] += r0.z * dv; acc0[3] += r0.w * dv;
                acc0[4] += r1.x * dv; acc0[5] += r1.y * dv; acc0[6] += r1.z * dv; acc0[7] += r1.w * dv;
                acc0[8] += r2.x * dv; acc0[9] += r2.y * dv;
            }
            if (e1 < e1e) {
                int s = csrL[e1++];
                const float4* rw = (const float4*)(h1p + s * RP);
                float4 r0 = rw[0], r1 = rw[1], r2 = rw[2];
                float dv = r2.z;
                acc1[0] += r0.x * dv; acc1[1] += r0.y * dv; acc1[2] += r0.z * dv; acc1[3] += r0.w * dv;
                acc1[4] += r1.x * dv; acc1[5] += r1.y * dv; acc1[6] += r1.z * dv; acc1[7] += r1.w * dv;
                acc1[8] += r2.x * dv; acc1[9] += r2.y * dv;
            }
        }
        const float4* q0 = (const float4*)(h1p + i0 * RP);
        const float4* q1 = (const float4*)(h1p + i1 * RP);
        float4 s00 = q0[0], s01 = q0[1], s02 = q0[2];
        float4 s10 = q1[0], s11 = q1[1], s12 = q1[2];
        float di0 = s02.z, d20 = di0 * di0;
        float di1 = s12.z, d21 = di1 * di1;
        float b1r[10];
#pragma unroll
        for (int j = 0; j < 10; j++) b1r[j] = b1[j];
        float v0[10], v1[10];
        v0[0] = acc0[0] * di0 + s00.x * d20 + b1r[0];
        v0[1] = acc0[1] * di0 + s00.y * d20 + b1r[1];
        v0[2] = acc0[2] * di0 + s00.z * d20 + b1r[2];
        v0[3] = acc0[3] * di0 + s00.w * d20 + b1r[3];
        v0[4] = acc0[4] * di0 + s01.x * d20 + b1r[4];
        v0[5] = acc0[5] * di0 + s01.y * d20 + b1r[5];
        v0[6] = acc0[6] * di0 + s01.z * d20 + b1r[6];
        v0[7] = acc0[7] * di0 + s01.w * d20 + b1r[7];
        v0[8] = acc0[8] * di0 + s02.x * d20 + b1r[8];
        v0[9] = acc0[9] * di0 + s02.y * d20 + b1r[9];
        v1[0] = acc1[0] * di1 + s10.x * d21 + b1r[0];
        v1[1] = acc1[1] * di1 + s10.y * d21 + b1r[1];
        v1[2] = acc1[2] * di1 + s10.z * d21 + b1r[2];
        v1[3] = acc1[3] * di1 + s10.w * d21 + b1r[3];
        v1[4] = acc1[4] * di1 + s11.x * d21 + b1r[4];
        v1[5] = acc1[5] * di1 + s11.y * d21 + b1r[5];
        v1[6] = acc1[6] * di1 + s11.z * d21 + b1r[6];
        v1[7] = acc1[7] * di1 + s11.w * d21 + b1r[7];
        v1[8] = acc1[8] * di1 + s12.x * d21 + b1r[8];
        v1[9] = acc1[9] * di1 + s12.y * d21 + b1r[9];
        float hs0 = 0.f, hs1 = 0.f;
#pragma unroll
        for (int j = 0; j < 10; j++) { float w = Ws[j]; hs0 += v0[j] * w; hs1 += v1[j] * w; }
        __syncthreads();   // all gathers complete before any in-place overwrite
        float4* w0 = (float4*)(h1p + i0 * RP);
        w0[0] = make_float4(v0[0], v0[1], v0[2], v0[3]);
        w0[1] = make_float4(v0[4], v0[5], v0[6], v0[7]);
        w0[2] = make_float4(v0[8], v0[9], di0, hs0);
        float4* w1 = (float4*)(h1p + i1 * RP);
        w1[0] = make_float4(v1[0], v1[1], v1[2], v1[3]);
        w1[1] = make_float4(v1[4], v1[5], v1[6], v1[7]);
        w1[2] = make_float4(v1[8], v1[9], di1, hs1);
    }
    __syncthreads();

    // ---- Phase C: scorer gather ((dinv,hs) b64), dual-node; keys; init topk
    {
        float bsv = bs[0];
        int i0 = tid, i1 = tid + 1024;
        float2 own0 = *(const float2*)(h1p + i0 * RP + 10);
        float2 own1 = *(const float2*)(h1p + i1 * RP + 10);
        int e0 = rsL[i0], e0e = rsL[i0 + 1];
        int e1 = rsL[i1], e1e = (i1 == NPG - 1) ? EPG : rsL[i1 + 1];
        float a0 = 0.f, a1 = 0.f;
        while (e0 < e0e || e1 < e1e) {
            if (e0 < e0e) { float2 dh = *(const float2*)(h1p + csrL[e0++] * RP + 10); a0 += dh.x * dh.y; }
            if (e1 < e1e) { float2 dh = *(const float2*)(h1p + csrL[e1++] * RP + 10); a1 += dh.x * dh.y; }
        }
        float sc0 = own0.x * a0 + own0.y * own0.x * own0.x + bsv;
        float sc1 = own1.x * a1 + own1.y * own1.x * own1.x + bsv;
        unsigned u0 = __float_as_uint(sc0);
        unsigned u1 = __float_as_uint(sc1);
        skL[i0] = (u0 & 0x80000000u) ? ~u0 : (u0 | 0x80000000u);
        skL[i1] = (u1 & 0x80000000u) ? ~u1 : (u1 | 0x80000000u);
        newLs[i0] = 0xFFFFu; newLs[i1] = 0xFFFFu;
        hist[i0] = 0; hist[i1] = 0;
    }
    int need = KSEL;
    unsigned prefix = 0;
    __syncthreads();

    // ---- Phase D: 3-level radix select (11/11/10 bits)
    for (int lv = 0; lv < 3; lv++) {
        for (int i = tid; i < NPG; i += 1024) {
            unsigned k = skL[i];
            bool match; unsigned bb;
            if (lv == 0)      { match = true;                  bb = k >> 21; }
            else if (lv == 1) { match = ((k >> 21) == prefix); bb = (k >> 10) & 0x7FFu; }
            else              { match = ((k >> 10) == prefix); bb = k & 0x3FFu; }
            if (match) atomicAdd(&hist[bb], 1);
        }
        __syncthreads();
        int b2 = tid * 2;
        int v0 = hist[b2], v1 = hist[b2 + 1];
        hist[b2] = 0; hist[b2 + 1] = 0;
        int s = v0 + v1;
        int incl = wave_incl_scan(s);
        if ((tid & 63) == 63) wsumL[wid] = incl;
        __syncthreads();
        if (tid == 0) {
            int a = 0;
#pragma unroll
            for (int w = 0; w < 16; w++) { int t = wsumL[w]; wsumL[w] = a; a += t; }
            totS = a;
        }
        __syncthreads();
        int base = wsumL[wid] + incl - s;
        int tot = totS;
        { int Sb = tot - base;        int Sb1 = Sb - v0; if (Sb >= need && Sb1 < need) { bselS = b2;     bneedS = need - Sb1; } }
        { int Sb = tot - (base + v0); int Sb1 = Sb - v1; if (Sb >= need && Sb1 < need) { bselS = b2 + 1; bneedS = need - Sb1; } }
        __syncthreads();
        if (lv == 0)      prefix = (unsigned)bselS;
        else if (lv == 1) prefix = (prefix << 11) | (unsigned)bselS;
        else              prefix = (prefix << 10) | (unsigned)bselS;
        need = bneedS;
        __syncthreads();
    }
    unsigned T = prefix;              // exact K-th largest key; need = #ties to take
    int greaterCnt = KSEL - need;

    // ---- Perm/newL assignment: ONE packed scan (greater in hi16, ties in lo16)
    {
        int b2 = tid * 2;
        unsigned k0 = skL[b2], k1 = skL[b2 + 1];
        int gt0 = k0 > T ? 1 : 0, gt1 = k1 > T ? 1 : 0;
        int eq0 = k0 == T ? 1 : 0, eq1 = k1 == T ? 1 : 0;
        int pack = ((gt0 + gt1) << 16) | (eq0 + eq1);
        int incl = wave_incl_scan(pack);
        if ((tid & 63) == 63) wsumL[wid] = incl;
        __syncthreads();
        if (tid == 0) {
            int a = 0;
#pragma unroll
            for (int w = 0; w < 16; w++) { int t = wsumL[w]; wsumL[w] = a; a += t; }
        }
        __syncthreads();
        int base = wsumL[wid] + incl - pack;
        int gb = base >> 16, eb = base & 0xFFFF;
        if (gt0) { permL[gb] = (unsigned short)b2; newLs[b2] = (unsigned short)gb; }
        if (gt1) { int r = gb + gt0; permL[r] = (unsigned short)(b2 + 1); newLs[b2 + 1] = (unsigned short)r; }
        if (eq0 && eb < need) { int p = greaterCnt + eb; permL[p] = (unsigned short)b2; newLs[b2] = (unsigned short)p; }
        if (eq1) { int r = eb + eq0; if (r < need) { int p = greaterCnt + r; permL[p] = (unsigned short)(b2 + 1); newLs[b2 + 1] = (unsigned short)p; } }
    }
    __syncthreads();

    // ---- Phase E2: gated pooled features, reg-staged; xp over h1p head
    {
        float4 rq0, rq1, rq2; float tt = 0.f;
        bool havep = (tid < KSEL);
        if (havep) {
            int iL = permL[tid];
            unsigned k = skL[iL];
            unsigned u = (k & 0x80000000u) ? (k & 0x7FFFFFFFu) : ~k;
            tt = tanhf(__uint_as_float(u));
            const float4* xr = (const float4*)(h1p + iL * RP);
            rq0 = xr[0]; rq1 = xr[1]; rq2 = xr[2];
        }
        __syncthreads();   // all x1 reads complete before xp overwrites h1p head
        if (havep) {
            float* xp = xpL + tid * 10;
            xp[0] = rq0.x * tt; xp[1] = rq0.y * tt; xp[2] = rq0.z * tt; xp[3] = rq0.w * tt;
            xp[4] = rq1.x * tt; xp[5] = rq1.y * tt; xp[6] = rq1.z * tt; xp[7] = rq1.w * tt;
            xp[8] = rq2.x * tt; xp[9] = rq2.y * tt;
        }
    }
    __syncthreads();

    // ---- Phase E1: filtered adjacency, chunk-of-8 prefetch (breaks csr->newL chain)
    for (int p = tid; p < KSEL; p += 1024) {
        int iL = permL[p];
        int p0 = rsL[iL], p1 = (iL == NPG - 1) ? EPG : rsL[iL + 1];
        int c = 0;
        int e = p0;
        while (e < p1) {
            int n = p1 - e; n = n > 8 ? 8 : n;
            int b8[8];
#pragma unroll
            for (int j = 0; j < 8; j++) b8[j] = csrL[e + (j < n ? j : 0)];
            unsigned short n8[8];
#pragma unroll
            for (int j = 0; j < 8; j++) n8[j] = newLs[b8[j]];
#pragma unroll
            for (int j = 0; j < 8; j++)
                if (j < n && n8[j] != 0xFFFFu && c < FCAP) fadjL[p * FCAP + c++] = n8[j];
            e += n;
        }
        fcntL[p] = c;
    }
    __syncthreads();

    // ---- Phase F: GAT features per (p, head)
    for (int t = tid; t < KSEL * NH; t += 1024) {
        int p = t / NH, hh = t - p * NH;
        float xi[10];
#pragma unroll
        for (int k = 0; k < 10; k++) xi[k] = xpL[p * 10 + k];
        float v[NC];
        float as_ = 0.f, ad_ = 0.f;
#pragma unroll
        for (int c = 0; c < NC; c++) {
            int j = hh * NC + c;
            float vv = 0.f;
#pragma unroll
            for (int k = 0; k < 10; k++) vv += xi[k] * Wg[k * HC + j];
            v[c] = vv;
            as_ += vv * a_srcw[j];
            ad_ += vv * a_dstw[j];
        }
        float4* hr = (float4*)(hfL + p * HC + hh * NC);
#pragma unroll
        for (int q = 0; q < 5; q++)
            hr[q] = make_float4(v[4 * q], v[4 * q + 1], v[4 * q + 2], v[4 * q + 3]);
        alsL[p * NH + hh] = as_;
        aldL[p * NH + hh] = ad_;
    }
    __syncthreads();

    // ---- Phase G: ONLINE single-pass softmax agg (anchored at lself) + butterfly readout
    {
        float res[NC];
#pragma unroll
        for (int rnd = 0; rnd < 2; rnd++) {
            int task = rnd == 0 ? tid : 1024 + tid;
            bool on = rnd == 0 || tid < KPAD;
            int hh = task >> 9, p = task & (KPAD - 1);
            if (on) {
                if (p < KSEL) {
                    float aldp = aldL[p * NH + hh];
                    float lself = leaky(alsL[p * NH + hh] + aldp);
                    int c = fcntL[p];
                    // self contributes weight exp(lself-lself)=1; alpha ratios identical
                    const float4* hp = (const float4*)(hfL + p * HC + hh * NC);
                    float4 r0 = hp[0], r1 = hp[1], r2 = hp[2], r3 = hp[3], r4 = hp[4];
                    float wsum = 1.f;
#pragma unroll
                    for (int e = 0; e < FCAP; e++) {
                        if (e < c) {
                            int idx = fadjL[p * FCAP + e];
                            float w = __expf(leaky(alsL[idx * NH + hh] + aldp) - lself);
                            wsum += w;
                            const float4* hq = (const float4*)(hfL + idx * HC + hh * NC);
                            float4 t0 = hq[0], t1 = hq[1], t2 = hq[2], t3 = hq[3], t4 = hq[4];
                            r0.x += w * t0.x; r0.y += w * t0.y; r0.z += w * t0.z; r0.w += w * t0.w;
                            r1.x += w * t1.x; r1.y += w * t1.y; r1.z += w * t1.z; r1.w += w * t1.w;
                            r2.x += w * t2.x; r2.y += w * t2.y; r2.z += w * t2.z; r2.w += w * t2.w;
                            r3.x += w * t3.x; r3.y += w * t3.y; r3.z += w * t3.z; r3.w += w * t3.w;
                            r4.x += w * t4.x; r4.y += w * t4.y; r4.z += w * t4.z; r4.w += w * t4.w;
                        }
                    }
                    float inv = 1.f / wsum;
                    res[0] = r0.x * inv;  res[1] = r0.y * inv;  res[2] = r0.z * inv;  res[3] = r0.w * inv;
                    res[4] = r1.x * inv;  res[5] = r1.y * inv;  res[6] = r1.z * inv;  res[7] = r1.w * inv;
                    res[8] = r2.x * inv;  res[9] = r2.y * inv;  res[10] = r2.z * inv; res[11] = r2.w * inv;
                    res[12] = r3.x * inv; res[13] = r3.y * inv; res[14] = r3.z * inv; res[15] = r3.w * inv;
                    res[16] = r4.x * inv; res[17] = r4.y * inv; res[18] = r4.z * inv; res[19] = r4.w * inv;
                } else {
#pragma unroll
                    for (int cc = 0; cc < NC; cc++) res[cc] = 0.f;
                }
#pragma unroll
                for (int cc = 0; cc < NC; cc++) {
                    float v = res[cc];
#pragma unroll
                    for (int d = 1; d < 64; d <<= 1) v += __shfl_xor(v, d, 64);
                    res[cc] = v;
                }
                if ((tid & 63) == 0) {
                    int slot = rnd == 0 ? hh * 8 + (wid & 7) : 16 + wid;
#pragma unroll
                    for (int cc = 0; cc < NC; cc++) wred[slot * NC + cc] = res[cc];
                }
            }
        }
    }
    __syncthreads();
    if (tid < HC) {
        int hh = tid / NC, c = tid - hh * NC;
        float a = 0.f;
#pragma unroll
        for (int w = 0; w < 8; w++) a += wred[(hh * 8 + w) * NC + c];
        goutL[tid] = a + (float)KSEL * bg[tid];
    }
    __syncthreads();

    // ---- Phase H: MLP + log_softmax
    if (tid < 30) {
        float s = bf1[tid];
#pragma unroll
        for (int k = 0; k < HC; k++) s += goutL[k] * Wf1[k * 30 + tid];
        hidL[tid] = s > 0.f ? s : 0.f;
    }
    __syncthreads();
    if (tid == 0) {
        float z[3];
#pragma unroll
        for (int j = 0; j < 3; j++) {
            float s = bf2[j];
            for (int k = 0; k < 30; k++) s += hidL[k] * Wf2[k * 3 + j];
            z[j] = s;
        }
        float m = fmaxf(z[0], fmaxf(z[1], z[2]));
        float lse = logf(expf(z[0] - m) + expf(z[1] - m) + expf(z[2] - m)) + m;
#pragma unroll
        for (int j = 0; j < 3; j++) out[g * 3 + j] = z[j] - lse;
    }
}

extern "C" void kernel_launch(void* const* d_in, const int* in_sizes, int n_in,
                              void* d_out, int out_size, void* d_ws, size_t ws_size,
                              hipStream_t stream) {
    const float* x     = (const float*)d_in[0];
    const int*   src   = (const int*)d_in[1];
    const int*   dst   = (const int*)d_in[2];
    const float* W1    = (const float*)d_in[4];
    const float* b1    = (const float*)d_in[5];
    const float* Ws    = (const float*)d_in[6];
    const float* bs    = (const float*)d_in[7];
    const float* Wg    = (const float*)d_in[8];
    const float* a_src = (const float*)d_in[9];
    const float* a_dst = (const float*)d_in[10];
    const float* bg    = (const float*)d_in[11];
    const float* Wf1   = (const float*)d_in[12];
    const float* bf1   = (const float*)d_in[13];
    const float* Wf2   = (const float*)d_in[14];
    const float* bf2   = (const float*)d_in[15];
    float* out = (float*)d_out;
    (void)d_ws; (void)ws_size;   // no workspace: x1 stays in LDS

    k_all<<<G, 1024, 0, stream>>>(x, src, dst, W1, b1, Ws, bs, Wg, a_src, a_dst,
                                  bg, Wf1, bf1, Wf2, bf2, out);
}